// Round 8
// baseline (626.649 us; speedup 1.0000x reference)
//
#include <hip/hip_runtime.h>

typedef _Float16 f16x8 __attribute__((ext_vector_type(8)));
typedef _Float16 f16x4 __attribute__((ext_vector_type(4)));
typedef float f32x4 __attribute__((ext_vector_type(4)));
typedef unsigned short u16x8 __attribute__((ext_vector_type(8)));
typedef unsigned int u32;

#define MFMA16H(a, b, c) __builtin_amdgcn_mfma_f32_16x16x32_f16(a, b, c, 0, 0, 0)

#if __has_builtin(__builtin_amdgcn_exp2f)
#define EXP2F(x) __builtin_amdgcn_exp2f(x)
#else
#define EXP2F(x) exp2f(x)
#endif

#define LOG2E 1.44269504088896340736f
#define SHIFT2 5.0f   // log2-shift: p' = 2^(l*log2e-5) in [2^-22, 2^12] -> fp16-safe

__device__ __forceinline__ unsigned short f2bf(float x) {
  unsigned u = __float_as_uint(x);
  u += 0x7FFF + ((u >> 16) & 1);   // round-to-nearest-even
  return (unsigned short)(u >> 16);
}
__device__ __forceinline__ float bf2f(unsigned short h) {
  return __uint_as_float(((unsigned)h) << 16);
}
__device__ __forceinline__ f16x8 ldh8(const _Float16* p) {
  return *reinterpret_cast<const f16x8*>(p);
}
__device__ __forceinline__ u16x8 ldu8(const unsigned short* p) {
  return *reinterpret_cast<const u16x8*>(p);
}

// ---------------- fused prep ----------------
// blocks [0,2048): mask -> permuted bf16(mask * -1e9 * log2e), fragment order
// blocks [2048, 2048+16384): fp32 -> fp16 conversions (q,k,v,wq,wk,wv,dw)
__global__ __launch_bounds__(256) void prep_kernel(
    const float* __restrict__ q, const float* __restrict__ k, const float* __restrict__ v,
    const float* __restrict__ wq, const float* __restrict__ wk, const float* __restrict__ wv,
    const float* __restrict__ dwt, const float* __restrict__ mask,
    _Float16* __restrict__ qf, _Float16* __restrict__ kf, _Float16* __restrict__ vf,
    _Float16* __restrict__ wqf, _Float16* __restrict__ wkf, _Float16* __restrict__ wvf,
    _Float16* __restrict__ dwf, unsigned short* __restrict__ mperm) {
  if (blockIdx.x < 2048) {
    const int blk = blockIdx.x;               // (b*32+qt)*32 + kt
    const int kt = blk & 31, bq = blk >> 5;
    const int b = bq >> 5, qt = bq & 31;
    const int lane = threadIdx.x;
    const int w = lane >> 6, lg = (lane >> 4) & 3, lr = lane & 15;
    const int q0 = qt * 64;
    const float cs = -1e9f * LOG2E;
    unsigned short vals[16];
#pragma unroll
    for (int c = 0; c < 4; ++c)
#pragma unroll
      for (int r = 0; r < 4; ++r) {
        const int qr = q0 + w * 16 + lg * 4 + r;
        const int kc = kt * 64 + c * 16 + lr;
        vals[c * 4 + r] = f2bf(mask[((size_t)b * 2048 + qr) * 2048 + kc] * cs);
      }
    uint4* out = reinterpret_cast<uint4*>(mperm) + ((size_t)blk * 256 + lane) * 2;
    out[0] = *reinterpret_cast<uint4*>(&vals[0]);
    out[1] = *reinterpret_cast<uint4*>(&vals[8]);
    return;
  }
  const int i = (blockIdx.x - 2048) * 256 + threadIdx.x;  // float4-group id
  const int r = i >> 18;  // 16 regions of 262144 groups
  const int j = i & 262143;
  const float* src;
  _Float16* dst;
  int off = 0;
  if (r < 4)       { src = q;   dst = qf;  off = r * 262144; }
  else if (r < 8)  { src = k;   dst = kf;  off = (r - 4) * 262144; }
  else if (r < 12) { src = v;   dst = vf;  off = (r - 8) * 262144; }
  else if (r == 12){ src = wq;  dst = wqf; }
  else if (r == 13){ src = wk;  dst = wkf; }
  else if (r == 14){ src = wv;  dst = wvf; }
  else             { src = dwt; dst = dwf; }
  const int g = off + j;
  float4 x = reinterpret_cast<const float4*>(src)[g];
  f16x4 h;
  h[0] = (_Float16)x.x; h[1] = (_Float16)x.y;
  h[2] = (_Float16)x.z; h[3] = (_Float16)x.w;
  reinterpret_cast<f16x4*>(dst)[g] = h;
}

// ---------------- GEMM body: y[m,n] = sum_k A[m,k]*B[n,k] + bias[n], fp16 in ----------------
// mode 0: out fp16 head-split [b,h,s,d]; mode 1: out fp16 [b,h,d,s]; mode 2: out fp32 [m,n]
__device__ __forceinline__ void gemm_body(
    int t, int mode, const _Float16* __restrict__ A, const _Float16* __restrict__ B,
    const float* __restrict__ bias, _Float16* __restrict__ out_h, float* __restrict__ out_f,
    _Float16* As, _Float16* Bs) {
  const int tid = threadIdx.x;
  const int tm = t & 31, tn = t >> 5;
  const int m0 = tm * 128, n0 = tn * 128;
  const int w = tid >> 6, l = tid & 63, lg = l >> 4, lr = l & 15;
  const int wr = w >> 1, wc = w & 1;
  const int srow = tid >> 2, scol = (tid & 3) * 8;

  f32x4 acc[4][4] = {};

  for (int kt = 0; kt < 32; ++kt) {
    const int k0 = kt * 32;
    uint4 ra[2], rb[2];
#pragma unroll
    for (int it = 0; it < 2; ++it) {
      const int row = it * 64 + srow;
      ra[it] = *reinterpret_cast<const uint4*>(A + (size_t)(m0 + row) * 1024 + k0 + scol);
      rb[it] = *reinterpret_cast<const uint4*>(B + (size_t)(n0 + row) * 1024 + k0 + scol);
    }
    __syncthreads();
#pragma unroll
    for (int it = 0; it < 2; ++it) {
      const int eo = (it * 256 + tid) * 8;
      *reinterpret_cast<uint4*>(As + eo) = ra[it];
      *reinterpret_cast<uint4*>(Bs + eo) = rb[it];
    }
    __syncthreads();

    f16x8 fa[4], fb[4];
#pragma unroll
    for (int i = 0; i < 4; ++i) {
      fa[i] = ldh8(As + (wr * 64 + i * 16 + lr) * 32 + lg * 8);
      fb[i] = ldh8(Bs + (wc * 64 + i * 16 + lr) * 32 + lg * 8);
    }
#pragma unroll
    for (int i = 0; i < 4; ++i)
#pragma unroll
      for (int j = 0; j < 4; ++j)
        acc[i][j] = MFMA16H(fa[i], fb[j], acc[i][j]);
  }

#pragma unroll
  for (int i = 0; i < 4; ++i) {
    const int mrow = m0 + wr * 64 + i * 16 + lg * 4;
#pragma unroll
    for (int j = 0; j < 4; ++j) {
      const int ncol = n0 + wc * 64 + j * 16 + lr;
      const float bv = bias[ncol];
#pragma unroll
      for (int r = 0; r < 4; ++r) {
        const int m = mrow + r;
        const float v = acc[i][j][r] + bv;
        if (mode == 2) {
          out_f[(size_t)m * 1024 + ncol] = v;
        } else {
          const int bb = m >> 11, s = m & 2047, hh = ncol >> 6, d = ncol & 63;
          if (mode == 0)
            out_h[((size_t)(bb * 16 + hh) * 2048 + s) * 64 + d] = (_Float16)v;
          else
            out_h[((size_t)(bb * 16 + hh) * 64 + d) * 2048 + s] = (_Float16)v;
        }
      }
    }
  }
}

// ---------------- fused projection GEMM (Q,K,V) ----------------
__global__ __launch_bounds__(256, 3) void proj_gemm_kernel(
    const _Float16* __restrict__ qf, const _Float16* __restrict__ kf, const _Float16* __restrict__ vf,
    const _Float16* __restrict__ wqf, const _Float16* __restrict__ wkf, const _Float16* __restrict__ wvf,
    const float* __restrict__ bq, const float* __restrict__ bk, const float* __restrict__ bv,
    _Float16* __restrict__ qhf, _Float16* __restrict__ khf, _Float16* __restrict__ vhT) {
  __shared__ __align__(16) _Float16 As[128 * 32];
  __shared__ __align__(16) _Float16 Bs[128 * 32];
  const int mode = blockIdx.x >> 8;
  const int t = blockIdx.x & 255;
  if (mode == 0)      gemm_body(t, 0, qf, wqf, bq, qhf, nullptr, As, Bs);
  else if (mode == 1) gemm_body(t, 0, kf, wkf, bk, khf, nullptr, As, Bs);
  else                gemm_body(t, 1, vf, wvf, bv, vhT, nullptr, As, Bs);
}

// ---------------- attention: QK^T + exp + p'-store (fp16) + row sums + PV ----------------
__global__ __launch_bounds__(256, 4) void attn_pv_kernel(
    const _Float16* __restrict__ qh, const _Float16* __restrict__ kh,
    const _Float16* __restrict__ vT,
    const float* __restrict__ rel_bias, const unsigned short* __restrict__ mperm,
    _Float16* __restrict__ o_h, _Float16* __restrict__ p16,
    float* __restrict__ scal) {
  __shared__ float rb2[2112];
  __shared__ __align__(16) _Float16 p_lds[64 * 76];

  const int bid = blockIdx.x;
  const int wg = ((bid & 7) << 7) | (bid >> 3);   // XCD-chunked: 4 bh per XCD
  const int bh = wg >> 5, qt = wg & 31;
  const int b = bh >> 4, h = bh & 15;
  const int q0 = qt * 64;
  const int tid = threadIdx.x;
  const int w = tid >> 6, l = tid & 63, lg = l >> 4, lr = l & 15;

  for (int t = tid; t < 2111; t += 256)
    rb2[t] = rel_bias[(q0 + t) * 16 + h] * LOG2E - SHIFT2;

  const size_t bh_off = (size_t)bh * 2048 * 64;
  const _Float16* qhb = qh + bh_off;
  const _Float16* khb = kh + bh_off;
  const _Float16* vTb = vT + bh_off;
  const unsigned short* mpb =
      mperm + (((size_t)(b * 32 + qt) * 32) * 256 + tid) * 16;
  _Float16* pbh = p16 + (size_t)bh * 2048 * 2048;

  f16x8 qf[2];
  {
    const size_t qrow = (size_t)(q0 + w * 16 + lr) * 64;
    qf[0] = ldh8(qhb + qrow + lg * 8);
    qf[1] = ldh8(qhb + qrow + 32 + lg * 8);
  }
  __syncthreads();  // rb2 ready (only barrier in the kernel)

  const int qbase = w * 16 + lg * 4;
  const float c1 = 0.125f * LOG2E;
  float sacc[4] = {0.f, 0.f, 0.f, 0.f};
  f32x4 acc_o[4] = {};

  for (int kt = 0; kt < 32; ++kt) {
    u16x8 m0v = ldu8(mpb + (size_t)kt * 4096);
    u16x8 m1v = ldu8(mpb + (size_t)kt * 4096 + 8);
#pragma unroll
    for (int c = 0; c < 4; ++c) {
      const int kc = kt * 64 + c * 16 + lr;
      const _Float16* kr = khb + (size_t)kc * 64 + lg * 8;
      f32x4 acc = {};
      acc = MFMA16H(qf[0], ldh8(kr), acc);
      acc = MFMA16H(qf[1], ldh8(kr + 32), acc);
#pragma unroll
      for (int r = 0; r < 4; ++r) {
        const float mbf = bf2f((c < 2) ? (unsigned short)m0v[(c & 1) * 4 + r]
                                       : (unsigned short)m1v[(c & 1) * 4 + r]);
        const float l2 = fmaf(acc[r], c1, rb2[qbase + r - kc + 2047]) + mbf;
        const float p = EXP2F(l2);
        sacc[r] += p;
        p_lds[(qbase + r) * 76 + c * 16 + lr] = (_Float16)p;
      }
    }
    // p rows are wave-local: same-wave lgkmcnt ordering only, no barrier
    f16x8 pf0 = ldh8(p_lds + (w * 16 + lr) * 76 + lg * 8);
    f16x8 pf1 = ldh8(p_lds + (w * 16 + lr) * 76 + 32 + lg * 8);
    // store unnormalized p' (fp16): 4 lanes (lg) cover one 64B row-chunk
    _Float16* prow = pbh + (size_t)(q0 + w * 16 + lr) * 2048 + kt * 64 + lg * 8;
    *reinterpret_cast<f16x8*>(prow) = pf0;
    *reinterpret_cast<f16x8*>(prow + 32) = pf1;
#pragma unroll
    for (int n = 0; n < 4; ++n) {
      const _Float16* vr = vTb + (size_t)(n * 16 + lr) * 2048 + kt * 64 + lg * 8;
      acc_o[n] = MFMA16H(pf0, ldh8(vr), acc_o[n]);
      acc_o[n] = MFMA16H(pf1, ldh8(vr + 32), acc_o[n]);
    }
  }

  float inv_s[4];
#pragma unroll
  for (int r = 0; r < 4; ++r) {
    float s = sacc[r];
    s += __shfl_xor(s, 1);
    s += __shfl_xor(s, 2);
    s += __shfl_xor(s, 4);
    s += __shfl_xor(s, 8);
    inv_s[r] = 1.0f / s;
    if (lr == 0) scal[(size_t)bh * 2048 + q0 + qbase + r] = inv_s[r];
  }

#pragma unroll
  for (int n = 0; n < 4; ++n)
#pragma unroll
    for (int r = 0; r < 4; ++r) {
      const int qr = q0 + qbase + r;
      const int d = n * 16 + lr;
      o_h[((size_t)(b * 2048 + qr) * 16 + h) * 64 + d] = (_Float16)(acc_o[n][r] * inv_s[r]);
    }
}

// ---------------- tail: dense GEMM (blocks<256) || fixup stream (rest) ----------------
__global__ __launch_bounds__(256) void tail_kernel(
    const _Float16* __restrict__ A, const _Float16* __restrict__ Bw,
    const float* __restrict__ bias, float* __restrict__ out_f,
    const _Float16* __restrict__ p16, const float* __restrict__ scal,
    float* __restrict__ attn) {
  __shared__ __align__(16) _Float16 As[128 * 32];
  __shared__ __align__(16) _Float16 Bs[128 * 32];
  if (blockIdx.x < 256) {
    gemm_body(blockIdx.x, 2, A, Bw, bias, nullptr, out_f, As, Bs);
    return;
  }
  // fixup: attn = fp16(p') * scal[row]
  f32x4* attnv = reinterpret_cast<f32x4*>(attn);
  const long long n8 = 16777216LL;  // 8-element groups
  const long long stride = (long long)(gridDim.x - 256) * 256;
  for (long long i = (long long)(blockIdx.x - 256) * 256 + threadIdx.x; i < n8; i += stride) {
    f16x8 p = reinterpret_cast<const f16x8*>(p16)[i];
    const float s = scal[i >> 8];   // 256 groups per 2048-wide row
    f32x4 lo, hi;
    lo[0] = (float)p[0] * s; lo[1] = (float)p[1] * s;
    lo[2] = (float)p[2] * s; lo[3] = (float)p[3] * s;
    hi[0] = (float)p[4] * s; hi[1] = (float)p[5] * s;
    hi[2] = (float)p[6] * s; hi[3] = (float)p[7] * s;
    __builtin_nontemporal_store(lo, attnv + 2 * i);
    __builtin_nontemporal_store(hi, attnv + 2 * i + 1);
  }
}

// ---------------- host ----------------
extern "C" void kernel_launch(void* const* d_in, const int* in_sizes, int n_in,
                              void* d_out, int out_size, void* d_ws, size_t ws_size,
                              hipStream_t stream) {
  const float* q = (const float*)d_in[0];
  const float* k = (const float*)d_in[1];
  const float* v = (const float*)d_in[2];
  const float* mask = (const float*)d_in[3];
  const float* wq_w = (const float*)d_in[4];
  const float* wq_b = (const float*)d_in[5];
  const float* wk_w = (const float*)d_in[6];
  const float* wk_b = (const float*)d_in[7];
  const float* wv_w = (const float*)d_in[8];
  const float* wv_b = (const float*)d_in[9];
  const float* dw = (const float*)d_in[10];
  const float* db = (const float*)d_in[11];
  const float* rel = (const float*)d_in[12];

  char* ws = (char*)d_ws;
  _Float16* qf_in = (_Float16*)(ws + 0);
  _Float16* kf_in = (_Float16*)(ws + 8388608);
  _Float16* vf_in = (_Float16*)(ws + 16777216);
  _Float16* wqf   = (_Float16*)(ws + 25165824);
  _Float16* wkf   = (_Float16*)(ws + 27262976);
  _Float16* wvf   = (_Float16*)(ws + 29360128);
  _Float16* dwf   = (_Float16*)(ws + 31457280);
  _Float16* qhf   = (_Float16*)(ws + 33554432);
  _Float16* khf   = (_Float16*)(ws + 41943040);
  _Float16* vhT   = (_Float16*)(ws + 50331648);
  _Float16* o_h   = (_Float16*)(ws + 58720256);
  float* scal     = (float*)(ws + 67108864);
  unsigned short* mperm = (unsigned short*)(ws + 67371008);
  _Float16* p16   = (_Float16*)(ws + 84148224);   // 268 MB unnormalized p'

  float* out = (float*)d_out;
  float* attn_out = out + 4194304;

  prep_kernel<<<18432, 256, 0, stream>>>(q, k, v, wq_w, wk_w, wv_w, dw, mask,
                                         qf_in, kf_in, vf_in, wqf, wkf, wvf, dwf, mperm);

  proj_gemm_kernel<<<768, 256, 0, stream>>>(qf_in, kf_in, vf_in, wqf, wkf, wvf,
                                            wq_b, wk_b, wv_b, qhf, khf, vhT);

  attn_pv_kernel<<<1024, 256, 0, stream>>>(qhf, khf, vhT, rel, mperm, o_h, p16, scal);

  tail_kernel<<<2304, 256, 0, stream>>>(o_h, dwf, db, out, p16, scal, attn_out);
}